// Round 5
// baseline (77.249 us; speedup 1.0000x reference)
//
#include <hip/hip_runtime.h>
#include <hip/hip_bf16.h>

#define HW 16384
#define W_IMG 128
#define BM_TOT 5
#define PRE 0.5101179482f   // (1/sqrt(8)) * log2(e): folded into Q so p = exp2(s-m)

typedef __attribute__((ext_vector_type(8))) short bf16x8;
typedef __attribute__((ext_vector_type(4))) float f32x4;

__device__ __forceinline__ short f2b(float f) {
    __hip_bfloat16 h = __float2bfloat16(f);
    union { __hip_bfloat16 h; short s; } c; c.h = h; return c.s;
}
__device__ __forceinline__ float b2f(short s) {
    union { unsigned u; float f; } v; v.u = ((unsigned)(unsigned short)s) << 16;
    return v.f;
}
__device__ __forceinline__ unsigned pk2(float a, float b) {   // -> v_cvt_pk_bf16_f32
    __hip_bfloat162 h = __float22bfloat162_rn(make_float2(a, b));
    union { __hip_bfloat162 h; unsigned u; } c; c.h = h; return c.u;
}

// ---------------------------------------------------------------------------
// Kernel 1: conv(3->64) + LayerNorm + MFMA 64x192 projection.
// K and Q use the transposed MFMA (D[ch][pix]); V the original (D[pix][ch]).
// All outputs staged in LDS, then stored as coalesced uint4:
//   kbuf  [bm][pix][ch]   (row-major, for k_attn K staging b128 reads)
//   qmid  [pix][ch]       pre-scaled bf16((q+pos_q)*PRE), center frame only
//   vbufP [bm][ch][pix]   PLANAR, so k_attn can stage V^T with vector ops
// Block 0 precomputes wcomb = w_rgb @ w_out and bf16 w_rgb.
// ---------------------------------------------------------------------------
__global__ __launch_bounds__(256) void k_qkv(
    const float* __restrict__ x, const float* __restrict__ w_high,
    const float* __restrict__ b_high, const float* __restrict__ gamma,
    const float* __restrict__ beta, const float* __restrict__ w_qkv,
    const float* __restrict__ w_out, const float* __restrict__ w_rgb,
    const float* __restrict__ pos_q,
    short* __restrict__ feat, short* __restrict__ qmid,
    short* __restrict__ kbuf, short* __restrict__ vbufP,
    short* __restrict__ wcombb, short* __restrict__ wrgbb)
{
    __shared__ short XS[64 * 72];
    __shared__ short TLq[64 * 72];
    __shared__ short TLk[64 * 72];
    __shared__ short TLv[64 * 72];
    const int tid = threadIdx.x, wv = tid >> 6, lane = tid & 63;
    const int blk = blockIdx.x;
    const int bm = blk >> 8;
    const int p0 = (blk & 255) * 64;
    const int pixbase = blk * 64;

    // ---- conv + LN for this wave's 16 pixels ----
    const int pw0 = wv * 16;
    float xv = 0.f;
    if ((lane >> 4) < 3)
        xv = x[(size_t)bm * 3 * HW + (lane >> 4) * HW + p0 + pw0 + (lane & 15)];
    const float wh0 = w_high[lane * 3], wh1 = w_high[lane * 3 + 1], wh2 = w_high[lane * 3 + 2];
    const float bh = b_high[lane], gm = gamma[lane], bt = beta[lane];
    #pragma unroll
    for (int t = 0; t < 16; ++t) {
        float x0 = __shfl(xv, t), x1 = __shfl(xv, 16 + t), x2 = __shfl(xv, 32 + t);
        float f = fmaf(wh0, x0, fmaf(wh1, x1, fmaf(wh2, x2, bh)));
        feat[((size_t)pixbase + pw0 + t) * 64 + lane] = f2b(f);
        float s = f, s2 = f * f;
        #pragma unroll
        for (int o = 32; o; o >>= 1) { s += __shfl_xor(s, o); s2 += __shfl_xor(s2, o); }
        float mu = s * 0.015625f;
        float var = s2 * 0.015625f - mu * mu;
        float xs = (f - mu) * rsqrtf(var + 1e-6f) * gm + bt;
        XS[(pw0 + t) * 72 + lane] = f2b(xs);
    }

    const int col = lane & 15, grp = lane >> 4;
    bf16x8 Bf[3][2];
    #pragma unroll
    for (int jj = 0; jj < 3; ++jj) {
        int jt = wv + jj * 4;
        #pragma unroll
        for (int kc = 0; kc < 2; ++kc) {
            const float* src = &w_qkv[(jt * 16 + col) * 64 + kc * 32 + grp * 8];
            union { bf16x8 v; unsigned u[4]; } tmp;
            #pragma unroll
            for (int i = 0; i < 4; ++i) tmp.u[i] = pk2(src[2 * i], src[2 * i + 1]);
            Bf[jj][kc] = tmp.v;
        }
    }
    __syncthreads();

    // ---- MFMA + LDS staging ----
    #pragma unroll
    for (int pt = 0; pt < 4; ++pt) {
        bf16x8 A0 = *(const bf16x8*)&XS[(pt * 16 + col) * 72 + grp * 8];
        bf16x8 A1 = *(const bf16x8*)&XS[(pt * 16 + col) * 72 + 32 + grp * 8];

        // K transposed: D[ch-in-tile = grp*4+i][pix-in-tile = col]
        f32x4 aK = {0.f, 0.f, 0.f, 0.f};
        aK = __builtin_amdgcn_mfma_f32_16x16x32_bf16(Bf[1][0], A0, aK, 0, 0, 0);
        aK = __builtin_amdgcn_mfma_f32_16x16x32_bf16(Bf[1][1], A1, aK, 0, 0, 0);
        uint2 kw;
        kw.x = pk2(aK[0], aK[1]); kw.y = pk2(aK[2], aK[3]);
        *(uint2*)&TLk[(pt * 16 + col) * 72 + wv * 16 + grp * 4] = kw;

        // V original: D[pix-in-tile = grp*4+i][ch-in-tile = col]
        f32x4 aV = {0.f, 0.f, 0.f, 0.f};
        aV = __builtin_amdgcn_mfma_f32_16x16x32_bf16(A0, Bf[2][0], aV, 0, 0, 0);
        aV = __builtin_amdgcn_mfma_f32_16x16x32_bf16(A1, Bf[2][1], aV, 0, 0, 0);
        uint2 vw;
        vw.x = pk2(aV[0], aV[1]); vw.y = pk2(aV[2], aV[3]);
        *(uint2*)&TLv[(wv * 16 + col) * 72 + pt * 16 + grp * 4] = vw;

        // Q transposed, + pos_q, * PRE (center frame only)
        if (bm == 2) {
            f32x4 aQ = {0.f, 0.f, 0.f, 0.f};
            aQ = __builtin_amdgcn_mfma_f32_16x16x32_bf16(Bf[0][0], A0, aQ, 0, 0, 0);
            aQ = __builtin_amdgcn_mfma_f32_16x16x32_bf16(Bf[0][1], A1, aQ, 0, 0, 0);
            int p = p0 + pt * 16 + col;
            int qq = ((p >> 7) & 7) * 8 + (p & 7);
            float4 pq = *(const float4*)&pos_q[qq * 64 + wv * 16 + grp * 4];
            uint2 qw;
            qw.x = pk2((aQ[0] + pq.x) * PRE, (aQ[1] + pq.y) * PRE);
            qw.y = pk2((aQ[2] + pq.z) * PRE, (aQ[3] + pq.w) * PRE);
            *(uint2*)&TLq[(pt * 16 + col) * 72 + wv * 16 + grp * 4] = qw;
        }
    }
    __syncthreads();

    // ---- coalesced copy-out: 512 uint4 per tensor ----
    #pragma unroll
    for (int it = 0; it < 2; ++it) {
        int j = it * 256 + tid;
        int row = j >> 3, seg = j & 7;          // row = pixel (K,Q) or channel (V)
        *(uint4*)&kbuf[((size_t)pixbase + row) * 64 + seg * 8] =
            *(const uint4*)&TLk[row * 72 + seg * 8];
        *(uint4*)&vbufP[((size_t)bm * 64 + row) * HW + p0 + seg * 8] =
            *(const uint4*)&TLv[row * 72 + seg * 8];
        if (bm == 2)
            *(uint4*)&qmid[((size_t)p0 + row) * 64 + seg * 8] =
                *(const uint4*)&TLq[row * 72 + seg * 8];
    }

    if (blk == 0) {
        for (int i = tid; i < 1024; i += 256) {
            short wc = 0, wr = 0;
            if (i < 192) {
                int c = i >> 6, e = i & 63;
                float a = 0.f;
                for (int e2 = 0; e2 < 64; ++e2)
                    a = fmaf(w_rgb[c * 64 + e2], w_out[e2 * 64 + e], a);
                wc = f2b(a);
                wr = f2b(w_rgb[i]);
            }
            wcombb[i] = wc;
            wrgbb[i] = wr;
        }
    }
}

// ---------------------------------------------------------------------------
// Kernel 2: windowed attention (MFMA) + fused projection epilogue.
// V^T staged from the PLANAR vbufP with vector loads/writes (no scalar
// transpose). Vt width 152 (16B rows, bank-stride 12 -> conflict-free);
// keys >=144 are covered by P=0, cols 144-151 zeroed to avoid NaN*0.
// ---------------------------------------------------------------------------
__global__ __launch_bounds__(512, 6) void k_attn(
    const short* __restrict__ qmid, const short* __restrict__ kbuf,
    const short* __restrict__ vbufP,
    const float* __restrict__ pos_k, const float* __restrict__ b_rgb,
    const short* __restrict__ feat, const short* __restrict__ wcombb,
    const short* __restrict__ wrgbb, float* __restrict__ outp)
{
    __shared__ char smem[48448];
    short* Klds = (short*)smem;                  // [144][72] bf16, K + pos_k
    short* Vt   = (short*)(smem + 20736);        // [64][152] bf16 + 16 slack
    short* OL   = (short*)smem;                  // overlay after sync: [64][72]

    const int tid = threadIdx.x, blk = blockIdx.x;
    const int bm = blk >> 8, widx = blk & 255;
    const int wi = widx >> 4, wj = widx & 15;
    const int head = tid >> 6, lane = tid & 63;
    const int col = lane & 15, grp = lane >> 4;

    // ---- stage K(+pos_k): key-fast order -> fully coalesced reads ----
    for (int idx = tid; idx < 1152; idx += 512) {
        int kk = idx >> 3, chunk = idx & 7;
        int r = kk / 12, c = kk - r * 12;
        int hh = wi * 8 - 2 + r, ww = wj * 8 - 2 + c;
        uint4 kraw = {0, 0, 0, 0};
        if ((unsigned)hh < 128u && (unsigned)ww < 128u)
            kraw = *(const uint4*)&kbuf[((size_t)bm * HW + hh * W_IMG + ww) * 64 + chunk * 8];
        const float* pk = &pos_k[kk * 64 + chunk * 8];
        float4 pk0 = *(const float4*)pk;
        float4 pk1 = *(const float4*)(pk + 4);
        union { uint4 q; short s[8]; } ku; ku.q = kraw;
        uint4 ko;
        ko.x = pk2(b2f(ku.s[0]) + pk0.x, b2f(ku.s[1]) + pk0.y);
        ko.y = pk2(b2f(ku.s[2]) + pk0.z, b2f(ku.s[3]) + pk0.w);
        ko.z = pk2(b2f(ku.s[4]) + pk1.x, b2f(ku.s[5]) + pk1.y);
        ko.w = pk2(b2f(ku.s[6]) + pk1.z, b2f(ku.s[7]) + pk1.w);
        *(uint4*)&Klds[kk * 72 + chunk * 8] = ko;
    }

    // ---- stage V^T from planar vbufP: task = (d, window-row) ----
    #pragma unroll
    for (int p = 0; p < 2; ++p) {
        int id = tid + p * 512;
        if (id < 768) {
            int d = id / 12, r = id - d * 12;
            int hh = wi * 8 - 2 + r;
            const short* src = vbufP + ((size_t)bm * 64 + d) * HW + hh * W_IMG + wj * 8;
            unsigned lf = 0, rt = 0; uint4 mid = {0, 0, 0, 0};
            if ((unsigned)hh < 128u) {
                mid = *(const uint4*)src;                      // cols 2..9
                if (wj > 0)  lf = *(const unsigned*)(src - 2); // cols 0,1
                if (wj < 15) rt = *(const unsigned*)(src + 8); // cols 10,11
            }
            short* dst = Vt + d * 152 + r * 12;
            *(uint2*)(dst)     = make_uint2(lf, mid.x);
            *(uint2*)(dst + 4) = make_uint2(mid.y, mid.z);
            *(uint2*)(dst + 8) = make_uint2(mid.w, rt);
        }
    }
    // zero pad cols [144,152) + 16-short slack (NaN-safety for P=0 region)
    if (tid < 128) *(uint2*)(Vt + (tid >> 1) * 152 + 144 + (tid & 1) * 4) = make_uint2(0u, 0u);
    if (tid < 8)   *(unsigned*)(Vt + 64 * 152 + tid * 2) = 0u;

    // ---- Q fragments: direct load, pos_q & scale pre-folded in k_qkv ----
    uint4 qraw[4] = {{0,0,0,0},{0,0,0,0},{0,0,0,0},{0,0,0,0}};
    if (grp == 0) {
        #pragma unroll
        for (int qt = 0; qt < 4; ++qt) {
            int q = qt * 16 + col;
            int pix = (wi * 8 + (q >> 3)) * W_IMG + wj * 8 + (q & 7);
            qraw[qt] = *(const uint4*)&qmid[(size_t)pix * 64 + head * 8];
        }
    }
    __syncthreads();

    // P slot buffer (per head, single-buffered, conflict-free)
    unsigned* PBh = (unsigned*)(smem + 40224 + head * 1024);
    const int slot_w = (grp * 16 + (col ^ grp)) * 4;
    const int g0 = 2 * (grp & 1);
    const int slotr1 = (g0 * 16 + (col ^ g0)) * 4 + (grp >> 1) * 2;
    const int slotr2 = ((g0 + 1) * 16 + (col ^ (g0 + 1))) * 4 + (grp >> 1) * 2;

    f32x4 oacc[4];
    float linv[4];

    #pragma unroll
    for (int qt = 0; qt < 4; ++qt) {
        union { bf16x8 v; uint4 r; } qu; qu.r = qraw[qt];
        const bf16x8 qf = qu.v;

        // ---- scores S^T: D[k'][q] over 9 key tiles ----
        f32x4 sc[9];
        __builtin_amdgcn_s_setprio(1);
        #pragma unroll
        for (int kt = 0; kt < 9; ++kt) {
            bf16x8 kf = *(const bf16x8*)&Klds[(kt * 16 + col) * 72 + head * 8];
            sc[kt] = __builtin_amdgcn_mfma_f32_16x16x32_bf16(kf, qf, (f32x4){0.f, 0.f, 0.f, 0.f}, 0, 0, 0);
        }
        __builtin_amdgcn_s_setprio(0);

        // ---- exact softmax, exp2-based ----
        float tm[9];
        #pragma unroll
        for (int t = 0; t < 9; ++t)
            tm[t] = fmaxf(fmaxf(sc[t][0], sc[t][1]), fmaxf(sc[t][2], sc[t][3]));
        float m = fmaxf(fmaxf(fmaxf(tm[0], tm[1]), fmaxf(tm[2], tm[3])),
                        fmaxf(fmaxf(tm[4], tm[5]), fmaxf(tm[6], tm[7])));
        m = fmaxf(m, tm[8]);
        m = fmaxf(m, __shfl_xor(m, 16));
        m = fmaxf(m, __shfl_xor(m, 32));

        float l = 0.f;
        unsigned pw[20];
        #pragma unroll
        for (int t = 0; t < 9; ++t) {
            float e0 = exp2f(sc[t][0] - m), e1 = exp2f(sc[t][1] - m);
            float e2 = exp2f(sc[t][2] - m), e3 = exp2f(sc[t][3] - m);
            l += (e0 + e1) + (e2 + e3);
            pw[2 * t]     = pk2(e0, e1);
            pw[2 * t + 1] = pk2(e2, e3);
        }
        pw[18] = 0u; pw[19] = 0u;
        l += __shfl_xor(l, 16);
        l += __shfl_xor(l, 32);
        linv[qt] = __builtin_amdgcn_rcpf(l);

        // ---- PV: O^T = V^T . P^T, P via single-buffer slot exchange ----
        *(uint4*)(PBh + slot_w) = make_uint4(pw[0], pw[1], pw[2], pw[3]);
        f32x4 oa = {0.f, 0.f, 0.f, 0.f};
        __builtin_amdgcn_s_setprio(1);
        #pragma unroll
        for (int kt2 = 0; kt2 < 5; ++kt2) {
            uint2 r1 = *(const uint2*)(PBh + slotr1);
            uint2 r2 = *(const uint2*)(PBh + slotr2);
            if (kt2 < 4)
                *(uint4*)(PBh + slot_w) =
                    make_uint4(pw[4 * kt2 + 4], pw[4 * kt2 + 5], pw[4 * kt2 + 6], pw[4 * kt2 + 7]);
            union { bf16x8 v; unsigned u[4]; } pf;
            pf.u[0] = r1.x; pf.u[1] = r1.y; pf.u[2] = r2.x; pf.u[3] = r2.y;
            bf16x8 vf = *(const bf16x8*)&Vt[(head * 8 + (lane & 7)) * 152 + kt2 * 32 + grp * 8];
            oa = __builtin_amdgcn_mfma_f32_16x16x32_bf16(vf, pf.v, oa, 0, 0, 0);
        }
        __builtin_amdgcn_s_setprio(0);
        oacc[qt] = oa;
    }

    __syncthreads();   // done with Klds -> overlay OL

    if (grp < 2) {
        #pragma unroll
        for (int qt = 0; qt < 4; ++qt) {
            float s = linv[qt];
            uint2 w;
            w.x = pk2(oacc[qt][0] * s, oacc[qt][1] * s);
            w.y = pk2(oacc[qt][2] * s, oacc[qt][3] * s);
            *(uint2*)&OL[(qt * 16 + col) * 72 + head * 8 + grp * 4] = w;
        }
    }
    __syncthreads();

    // ---- fused epilogue: rgb = O@wcomb^T + feat@w_rgb^T + b_rgb (waves 0-3) ----
    if (head < 4) {
        const int qt = head;
        f32x4 acc = {0.f, 0.f, 0.f, 0.f};
        const int q = qt * 16 + col;
        const int pixA = (wi * 8 + (q >> 3)) * W_IMG + wj * 8 + (q & 7);
        #pragma unroll
        for (int kc = 0; kc < 2; ++kc) {
            bf16x8 ao = *(const bf16x8*)&OL[(qt * 16 + col) * 72 + kc * 32 + grp * 8];
            bf16x8 bo = *(const bf16x8*)&wcombb[col * 64 + kc * 32 + grp * 8];
            acc = __builtin_amdgcn_mfma_f32_16x16x32_bf16(ao, bo, acc, 0, 0, 0);
            bf16x8 af = *(const bf16x8*)&feat[((size_t)bm * HW + pixA) * 64 + kc * 32 + grp * 8];
            bf16x8 bf_ = *(const bf16x8*)&wrgbb[col * 64 + kc * 32 + grp * 8];
            acc = __builtin_amdgcn_mfma_f32_16x16x32_bf16(af, bf_, acc, 0, 0, 0);
        }
        if (col < 3) {
            float br = b_rgb[col];
            #pragma unroll
            for (int i = 0; i < 4; ++i) {
                int qs = qt * 16 + grp * 4 + i;
                int pix = (wi * 8 + (qs >> 3)) * W_IMG + wj * 8 + (qs & 7);
                outp[(size_t)bm * 3 * HW + col * HW + pix] = acc[i] + br;
            }
        }
    }
}

// ---------------------------------------------------------------------------
extern "C" void kernel_launch(void* const* d_in, const int* in_sizes, int n_in,
                              void* d_out, int out_size, void* d_ws, size_t ws_size,
                              hipStream_t stream) {
    const float* x      = (const float*)d_in[0];
    const float* w_high = (const float*)d_in[1];
    const float* b_high = (const float*)d_in[2];
    const float* gamma  = (const float*)d_in[3];
    const float* beta   = (const float*)d_in[4];
    const float* w_qkv  = (const float*)d_in[5];
    const float* pos_q  = (const float*)d_in[6];
    const float* pos_k  = (const float*)d_in[7];
    const float* w_out  = (const float*)d_in[8];
    const float* w_rgb  = (const float*)d_in[9];
    const float* b_rgb  = (const float*)d_in[10];
    float* out = (float*)d_out;

    short* feat   = (short*)d_ws;
    short* kbuf   = feat + (size_t)BM_TOT * HW * 64;
    short* vbufP  = kbuf + (size_t)BM_TOT * HW * 64;
    short* qmid   = vbufP + (size_t)BM_TOT * HW * 64;
    short* wcombb = qmid + (size_t)HW * 64;
    short* wrgbb  = wcombb + 1024;

    k_qkv<<<BM_TOT * 256, 256, 0, stream>>>(x, w_high, b_high, gamma, beta, w_qkv,
                                            w_out, w_rgb, pos_q,
                                            feat, qmid, kbuf, vbufP, wcombb, wrgbb);
    k_attn<<<BM_TOT * 256, 512, 0, stream>>>(qmid, kbuf, vbufP, pos_k,
                                             b_rgb, feat, wcombb, wrgbb, out);
}